// Round 7
// baseline (1328.718 us; speedup 1.0000x reference)
//
#include <hip/hip_runtime.h>

typedef __bf16 bf16;
typedef __bf16 bf16x4 __attribute__((ext_vector_type(4)));
typedef __bf16 bf16x8 __attribute__((ext_vector_type(8)));
typedef float floatx4 __attribute__((ext_vector_type(4)));

#define BB 8
#define LL 2048
#define DD 2048
#define NHH 32
#define HDD 64

#define MFMA16(a, b, c) __builtin_amdgcn_mfma_f32_16x16x32_bf16(a, b, c, 0, 0, 0)

// async global->LDS DMA, 16B per lane; dest = wave-uniform base + lane*16
__device__ __forceinline__ void gl_lds16(const void* g, void* l) {
  __builtin_amdgcn_global_load_lds((const __attribute__((address_space(1))) void*)g,
                                   (__attribute__((address_space(3))) void*)l, 16, 0, 0);
}

// ---------------- fp32 -> bf16 bulk cast ----------------
__global__ __launch_bounds__(256) void cast_bf16(const float* __restrict__ src,
                                                 bf16* __restrict__ dst)
{
  size_t i = ((size_t)blockIdx.x * 256 + threadIdx.x) * 8;
  floatx4 a = *(const floatx4*)(src + i);
  floatx4 b = *(const floatx4*)(src + i + 4);
  bf16x8 v;
  v[0] = (bf16)a[0]; v[1] = (bf16)a[1]; v[2] = (bf16)a[2]; v[3] = (bf16)a[3];
  v[4] = (bf16)b[0]; v[5] = (bf16)b[1]; v[6] = (bf16)b[2]; v[7] = (bf16)b[3];
  *(bf16x8*)(dst + i) = v;
}

// ---------------- weight transpose + cast: WT[n][k] = (bf16)W[k][n] ----------------
__global__ __launch_bounds__(256) void transpose1(const float* __restrict__ src,
                                                  bf16* __restrict__ dst)
{
  __shared__ float tile[64][65];
  const int t = threadIdx.x;
  const int col = t & 63, rw = t >> 6;
  const int bx = blockIdx.x * 64, by = blockIdx.y * 64;
  for (int i = rw; i < 64; i += 4)
    tile[i][col] = src[(size_t)(by + i) * DD + bx + col];
  __syncthreads();
  for (int i = rw; i < 64; i += 4)
    dst[(size_t)(bx + i) * DD + by + col] = (bf16)tile[col][i];
}

// ---------------- fused QKV GEMM: {Q,K,V}[16384][2048] = X x {wq,wk,wv} --------------
// One A tile staged per k-step, multiplied by THREE B panels -> 3x MFMA per unit of
// staging+barrier cost, 3x fewer A re-streams through L3.
// 512 threads, 8 waves (2M x 4N), tile 128x128 per weight, BK=64, LDS 64KB.
// AFP==0: A = bf16 Xb, DMA-staged.  AFP==1: A = fp32 X, reg-staged with cast.
// XOR chunk-swizzle (chunk ^= row&7) on source/write and on the ds_read side.
// RoPE fused into Q and K epilogues.
template<int AFP>
__global__ __launch_bounds__(512) void gemm_qkv(const void* __restrict__ Xv,
    const bf16* __restrict__ BTq, const bf16* __restrict__ BTk,
    const bf16* __restrict__ BTv,
    bf16* __restrict__ Qo, bf16* __restrict__ Ko, bf16* __restrict__ Vo)
{
  constexpr int Kd = 2048;
  __shared__ alignas(16) bf16 As[128 * 64];      // 16 KB
  __shared__ alignas(16) bf16 Bs[3][128 * 64];   // 48 KB
  const int t = threadIdx.x;
  // XCD-aware swizzle: 2048 wgs, 2048%8==0 -> bijective remap.
  const int id = blockIdx.y * 16 + blockIdx.x;
  const int swz = (id & 7) * 256 + (id >> 3);
  const int bn = swz & 15, bm = swz >> 4;
  const int wv = t >> 6, lane = t & 63;
  const int q = lane >> 4, i16 = lane & 15;
  const int wm = wv >> 2, wn = wv & 3;           // 2(M) x 4(N) wave grid
  const int srow = lane >> 3, scol = lane & 7;   // staging sub-coords

  floatx4 acc[3][4][2] = {};                     // 96 VGPR
  char* AsB = (char*)As + wv * 2048;
  const bf16* Bg[3] = {BTq, BTk, BTv};

  for (int k0 = 0; k0 < Kd; k0 += 64) {
    // ---- stage A (one tile, shared by all three weights) ----
#pragma unroll
    for (int i = 0; i < 2; ++i) {
      int r = (wv * 2 + i) * 8 + srow;           // 0..127
      int cc = scol ^ (r & 7);                   // inverse-swizzled source chunk
      if (AFP == 0) {
        gl_lds16((const bf16*)Xv + (size_t)(bm * 128 + r) * Kd + k0 + cc * 8,
                 AsB + i * 1024);
      } else {
        const float* src = (const float*)Xv + (size_t)(bm * 128 + r) * Kd + k0 + cc * 8;
        floatx4 f0 = *(const floatx4*)src;
        floatx4 f1 = *(const floatx4*)(src + 4);
        bf16x8 v;
        v[0] = (bf16)f0[0]; v[1] = (bf16)f0[1]; v[2] = (bf16)f0[2]; v[3] = (bf16)f0[3];
        v[4] = (bf16)f1[0]; v[5] = (bf16)f1[1]; v[6] = (bf16)f1[2]; v[7] = (bf16)f1[3];
        *(bf16x8*)((char*)As + (wv * 2 + i) * 1024 + lane * 16) = v;
      }
    }
    // ---- stage B for the three weights ----
#pragma unroll
    for (int w = 0; w < 3; ++w)
#pragma unroll
      for (int i = 0; i < 2; ++i) {
        int r = (wv * 2 + i) * 8 + srow;
        int cc = scol ^ (r & 7);
        gl_lds16(Bg[w] + (size_t)(bn * 128 + r) * Kd + k0 + cc * 8,
                 (char*)Bs[w] + wv * 2048 + i * 1024);
      }
    __syncthreads();

#pragma unroll
    for (int kk = 0; kk < 2; ++kk) {
      bf16x8 af[4];
#pragma unroll
      for (int mt = 0; mt < 4; ++mt) {
        int r = wm * 64 + mt * 16 + i16;
        af[mt] = *(const bf16x8*)&As[r * 64 + ((kk * 4 + q) ^ (r & 7)) * 8];
      }
#pragma unroll
      for (int w = 0; w < 3; ++w) {
        bf16x8 bfr[2];
#pragma unroll
        for (int nt = 0; nt < 2; ++nt) {
          int r = wn * 32 + nt * 16 + i16;
          bfr[nt] = *(const bf16x8*)&Bs[w][r * 64 + ((kk * 4 + q) ^ (r & 7)) * 8];
        }
#pragma unroll
        for (int mt = 0; mt < 4; ++mt)
#pragma unroll
          for (int nt = 0; nt < 2; ++nt)
            acc[w][mt][nt] = MFMA16(af[mt], bfr[nt], acc[w][mt][nt]);
      }
    }
    __syncthreads();
  }

  // ---- epilogue: RoPE for Q,K; QKV-layout bf16 stores ----
  float invf[2];
#pragma unroll
  for (int nt = 0; nt < 2; ++nt) {
    int col = bn * 128 + wn * 32 + nt * 16 + i16;
    int i = (col >> 1) & 31;
    invf[nt] = __expf(-(float)i * 0.28782313662425573f);  // ln(10000)/32
  }
#pragma unroll
  for (int w = 0; w < 3; ++w) {
    bf16* Co = (w == 0) ? Qo : (w == 1) ? Ko : Vo;
#pragma unroll
    for (int mt = 0; mt < 4; ++mt)
#pragma unroll
      for (int nt = 0; nt < 2; ++nt)
#pragma unroll
        for (int rg = 0; rg < 4; ++rg) {
          int row = bm * 128 + wm * 64 + mt * 16 + q * 4 + rg;
          int col = bn * 128 + wn * 32 + nt * 16 + i16;
          float v = acc[w][mt][nt][rg];
          if (w < 2) {
            float o = __shfl_xor(v, 1, 64);
            float sn, cs;
            __sincosf((float)(row & 2047) * invf[nt], &sn, &cs);
            v = (i16 & 1) ? (v * cs + o * sn) : (v * cs - o * sn);
          }
          int b = row >> 11, l = row & 2047;
          int h = col >> 6, f = col & 63;
          Co[((size_t)(b * NHH + h) * LL + l) * HDD + f] = (bf16)v;
        }
  }
}

// ---------------- GEMM (known-good, used for the final Wo matmul) ----------------
template<int AIDX, int EPI, int RP>
__global__ __launch_bounds__(256) void gemm_bt(const bf16* __restrict__ Ab,
    const bf16* __restrict__ BT, void* __restrict__ Cv)
{
  constexpr int Kd = 2048;
  __shared__ alignas(16) bf16 As[128 * 64];
  __shared__ alignas(16) bf16 Bs[128 * 64];
  const int t = threadIdx.x;
  const int id = blockIdx.y * 16 + blockIdx.x;
  const int swz = (id & 7) * 256 + (id >> 3);
  const int bn = swz & 15, bm = swz >> 4;
  const int wave = t >> 6, lane = t & 63;
  const int m16 = lane & 15, quad = lane >> 4;
  floatx4 acc[2][8] = {};
  const int r0 = t >> 3;
  const int scc = (t & 7) ^ (r0 & 7);
  const bf16* Bb = BT + (size_t)(bn * 128) * Kd;
  char* AsB = (char*)As + wave * 1024;
  char* BsB = (char*)Bs + wave * 1024;

  for (int k0 = 0; k0 < Kd; k0 += 64) {
    for (int i = 0; i < 4; ++i) {
      int r = r0 + 32 * i;
      int col = k0 + scc * 8;
      const bf16* ga;
      if (AIDX == 0) {
        ga = Ab + (size_t)(bm * 128 + r) * Kd + col;
      } else {
        int R = bm * 128 + r;
        int b = R >> 11, l = R & 2047;
        int h = col >> 6, f = col & 63;
        ga = Ab + (((size_t)(b * NHH + h) * LL + l) * HDD + f);
      }
      gl_lds16(ga, AsB + i * 4096);
      gl_lds16(Bb + (size_t)r * Kd + col, BsB + i * 4096);
    }
    __syncthreads();
    const int sw = m16 & 7;
    for (int kk = 0; kk < 2; ++kk) {
      bf16x8 af[2], bfr[8];
      const int c = ((kk * 4 + quad) ^ sw) * 8;
      for (int mt = 0; mt < 2; ++mt)
        af[mt] = *(const bf16x8*)&As[(wave * 32 + mt * 16 + m16) * 64 + c];
      for (int nt = 0; nt < 8; ++nt)
        bfr[nt] = *(const bf16x8*)&Bs[(nt * 16 + m16) * 64 + c];
      for (int mt = 0; mt < 2; ++mt)
        for (int nt = 0; nt < 8; ++nt)
          acc[mt][nt] = MFMA16(af[mt], bfr[nt], acc[mt][nt]);
    }
    __syncthreads();
  }

  float invf[8];
  if (RP) {
#pragma unroll
    for (int nt = 0; nt < 8; ++nt) {
      int col = bn * 128 + nt * 16 + m16;
      int i = (col >> 1) & 31;
      invf[nt] = __expf(-(float)i * 0.28782313662425573f);
    }
  }

  for (int mt = 0; mt < 2; ++mt)
    for (int nt = 0; nt < 8; ++nt)
      for (int rg = 0; rg < 4; ++rg) {
        int row = bm * 128 + wave * 32 + mt * 16 + quad * 4 + rg;
        int col = bn * 128 + nt * 16 + m16;
        float v = acc[mt][nt][rg];
        if (RP) {
          float o = __shfl_xor(v, 1, 64);
          float sn, cs;
          __sincosf((float)(row & 2047) * invf[nt], &sn, &cs);
          v = (m16 & 1) ? (v * cs + o * sn) : (v * cs - o * sn);
        }
        if (EPI == 0) {
          ((float*)Cv)[(size_t)row * DD + col] = v;
        } else {
          int b = row >> 11, l = row & 2047;
          int h = col >> 6, f = col & 63;
          ((bf16*)Cv)[((size_t)(b * NHH + h) * LL + l) * HDD + f] = (bf16)v;
        }
      }
}

// ---------------- TTT scan v3 (round-6, unchanged): 4 waves, 3 barriers/chunk ---------
__global__ __launch_bounds__(256) void ttt_scan(
    const bf16* Q, const bf16* __restrict__ Kx,
    const bf16* __restrict__ V, const float* __restrict__ W1g,
    const float* __restrict__ b1g, const float* __restrict__ gw,
    const float* __restrict__ gb, bf16* O)
{
  const int bh = blockIdx.x, h = bh & 31;
  const int t = threadIdx.x;
  const int wave = t >> 6, lane = t & 63;
  const int q = lane >> 4, i16 = lane & 15;
  const int kr = t >> 4, sr = t & 15, f0 = sr * 4;

  __shared__ alignas(16) bf16 W1Th[64 * 72];
  __shared__ alignas(16) bf16 W1Tl[64 * 72];
  __shared__ alignas(16) bf16 xkTs[64 * 24];
  __shared__ alignas(16) bf16 gTh[64 * 24];
  __shared__ alignas(16) bf16 gTl[64 * 24];
  __shared__ alignas(16) bf16 Pm[16 * 24];
  __shared__ alignas(16) float Z1s[2][16 * 68];

  floatx4 accW[4];
  const float* Wg = W1g + (size_t)h * 4096;
  for (int mt = 0; mt < 4; ++mt)
    for (int r = 0; r < 4; ++r)
      accW[mt][r] = Wg[(16 * mt + 4 * q + r) * 64 + 16 * wave + i16];
  float b1r = b1g[h * 64 + 16 * wave + i16];

  for (int mt = 0; mt < 4; ++mt) {
    bf16x4 h4, l4;
    for (int r = 0; r < 4; ++r) {
      float w = accW[mt][r];
      bf16 hi = (bf16)w;
      h4[r] = hi; l4[r] = (bf16)(w - (float)hi);
    }
    int base = (16 * wave + i16) * 72 + 16 * mt + 4 * q;
    *(bf16x4*)&W1Th[base] = h4;
    *(bf16x4*)&W1Tl[base] = l4;
  }

  float gq[4], bq[4];
  for (int j = 0; j < 4; ++j) {
    gq[j] = gw[h * 64 + f0 + j];
    bq[j] = gb[h * 64 + f0 + j];
  }
  float etar[4];
  for (int r = 0; r < 4; ++r) etar[r] = 1.0f / (float)(4 * q + r + 1);

  const size_t qbase = (size_t)bh * (LL * HDD);
  const int foff = i16 * 64 + q * 8;
  const int poff = kr * 64 + f0;

  bf16x8 ak0 = *(const bf16x8*)(Kx + qbase + foff);
  bf16x8 ak1 = *(const bf16x8*)(Kx + qbase + foff + 32);
  bf16x8 aq0 = *(const bf16x8*)(Q  + qbase + foff);
  bf16x8 aq1 = *(const bf16x8*)(Q  + qbase + foff + 32);
  bf16x4 rq = *(const bf16x4*)(Q  + qbase + poff);
  bf16x4 rk = *(const bf16x4*)(Kx + qbase + poff);
  bf16x4 rv = *(const bf16x4*)(V  + qbase + poff);

  __syncthreads();

  for (int c = 0; c < 128; ++c) {
    const int pb = c & 1;
    for (int j = 0; j < 4; ++j)
      xkTs[(f0 + j) * 24 + kr] = (bf16)((float)rk[j] * -0.0625f);

    bf16x8 whi[2], wlo[2];
    {
      int wb = (16 * wave + i16) * 72 + q * 8;
      whi[0] = *(const bf16x8*)&W1Th[wb];
      whi[1] = *(const bf16x8*)&W1Th[wb + 32];
      wlo[0] = *(const bf16x8*)&W1Tl[wb];
      wlo[1] = *(const bf16x8*)&W1Tl[wb + 32];
    }
    {
      floatx4 z = {b1r, b1r, b1r, b1r};
      z = MFMA16(ak0, whi[0], z);
      z = MFMA16(ak1, whi[1], z);
      z = MFMA16(ak0, wlo[0], z);
      z = MFMA16(ak1, wlo[1], z);
      for (int r = 0; r < 4; ++r)
        Z1s[pb][(4 * q + r) * 68 + 16 * wave + i16] = z[r];
    }
    if (wave == 0) {
      floatx4 at = {};
      at = MFMA16(aq0, ak0, at);
      at = MFMA16(aq1, ak1, at);
      for (int r = 0; r < 4; ++r) {
        int krow = 4 * q + r;
        float pv = (i16 <= krow) ? -(at[r] + 1.0f) * etar[r] : 0.0f;
        Pm[krow * 24 + i16] = (bf16)pv;
      }
    }
    __syncthreads();   // barrier B

    {
      floatx4 z4 = *(const floatx4*)&Z1s[pb][kr * 68 + f0];
      float tg[4], sum = 0.f, ssq = 0.f;
      for (int j = 0; j < 4; ++j) {
        tg[j] = (float)rv[j] - (float)rk[j];
        sum += z4[j]; ssq += z4[j] * z4[j];
      }
      for (int m = 1; m < 16; m <<= 1) { sum += __shfl_xor(sum, m, 64); ssq += __shfl_xor(ssq, m, 64); }
      float mu = sum * (1.f / 64.f);
      float var = ssq * (1.f / 64.f) - mu * mu;
      float rstd = rsqrtf(var + 1e-6f);
      float xh[4], gx[4], s1 = 0.f, s2 = 0.f;
      for (int j = 0; j < 4; ++j) {
        xh[j] = (z4[j] - mu) * rstd;
        float go = gq[j] * xh[j] + bq[j] - tg[j];
        gx[j] = go * gq[j];
        s1 += gx[j]; s2 += gx[j] * xh[j];
      }
      for (int m = 1; m < 16; m <<= 1) { s1 += __shfl_xor(s1, m, 64); s2 += __shfl_xor(s2, m, 64); }
      for (int j = 0; j < 4; ++j) {
        float gr = (64.f * gx[j] - s1 - xh[j] * s2) * (rstd * (1.f / 64.f));
        bf16 hi = (bf16)gr;
        gTh[(f0 + j) * 24 + kr] = hi;
        gTl[(f0 + j) * 24 + kr] = (bf16)(gr - (float)hi);
      }
    }
    __syncthreads();   // barrier C

    const size_t nb = qbase + (size_t)(c + 1) * 1024;
    bf16x8 nak0 = *(const bf16x8*)(Kx + nb + foff);
    bf16x8 nak1 = *(const bf16x8*)(Kx + nb + foff + 32);
    bf16x8 naq0 = *(const bf16x8*)(Q  + nb + foff);
    bf16x8 naq1 = *(const bf16x8*)(Q  + nb + foff + 32);
    bf16x4 nrq = *(const bf16x4*)(Q  + nb + poff);
    bf16x4 nrk = *(const bf16x4*)(Kx + nb + poff);
    bf16x4 nrv = *(const bf16x4*)(V  + nb + poff);

    {
      bf16x8 pf  = *(const bf16x8*)&Pm[i16 * 24 + (q & 1) * 8];
      const bf16* gT = (q < 2) ? gTh : gTl;
      bf16x8 bgp = *(const bf16x8*)&gT[(16 * wave + i16) * 24 + (q & 1) * 8];
      floatx4 zb = {b1r, b1r, b1r, b1r};
      zb = MFMA16(aq0, whi[0], zb);
      zb = MFMA16(aq1, whi[1], zb);
      zb = MFMA16(aq0, wlo[0], zb);
      zb = MFMA16(aq1, wlo[1], zb);
      zb = MFMA16(pf, bgp, zb);
      for (int r = 0; r < 4; ++r)
        Z1s[pb][(4 * q + r) * 68 + 16 * wave + i16] = zb[r];

      for (int mt = 0; mt < 4; ++mt) {
        bf16x8 axk = *(const bf16x8*)&xkTs[(16 * mt + i16) * 24 + (q & 1) * 8];
        accW[mt] = MFMA16(axk, bgp, accW[mt]);
      }
      for (int mt = 0; mt < 4; ++mt) {
        bf16x4 h4, l4;
        for (int r = 0; r < 4; ++r) {
          float w = accW[mt][r];
          bf16 hi = (bf16)w;
          h4[r] = hi; l4[r] = (bf16)(w - (float)hi);
        }
        int base = (16 * wave + i16) * 72 + 16 * mt + 4 * q;
        *(bf16x4*)&W1Th[base] = h4;
        *(bf16x4*)&W1Tl[base] = l4;
      }
      {
        const bf16* rh = &gTh[(16 * wave + i16) * 24];
        const bf16* rl = &gTl[(16 * wave + i16) * 24];
        bf16x8 a0 = *(const bf16x8*)rh, a1 = *(const bf16x8*)(rh + 8);
        bf16x8 a2 = *(const bf16x8*)rl, a3 = *(const bf16x8*)(rl + 8);
        float s = 0.f;
        for (int j = 0; j < 8; ++j)
          s += (float)a0[j] + (float)a1[j] + (float)a2[j] + (float)a3[j];
        b1r -= 0.0625f * s;
      }
    }
    __syncthreads();   // barrier D

    {
      floatx4 z4 = *(const floatx4*)&Z1s[pb][kr * 68 + f0];
      float sum = 0.f, ssq = 0.f;
      for (int j = 0; j < 4; ++j) { sum += z4[j]; ssq += z4[j] * z4[j]; }
      for (int m = 1; m < 16; m <<= 1) { sum += __shfl_xor(sum, m, 64); ssq += __shfl_xor(ssq, m, 64); }
      float mu = sum * (1.f / 64.f);
      float var = ssq * (1.f / 64.f) - mu * mu;
      float rstd = rsqrtf(var + 1e-6f);
      bf16x4 o4;
      for (int j = 0; j < 4; ++j)
        o4[j] = (bf16)((float)rq[j] + gq[j] * ((z4[j] - mu) * rstd) + bq[j]);
      *(bf16x4*)(O + qbase + (size_t)c * 1024 + poff) = o4;
    }
    ak0 = nak0; ak1 = nak1; aq0 = naq0; aq1 = naq1;
    rq = nrq; rk = nrk; rv = nrv;
  }
}

extern "C" void kernel_launch(void* const* d_in, const int* in_sizes, int n_in,
                              void* d_out, int out_size, void* d_ws, size_t ws_size,
                              hipStream_t stream)
{
  const float* X  = (const float*)d_in[0];
  const float* wq = (const float*)d_in[1];
  const float* wk = (const float*)d_in[2];
  const float* wv = (const float*)d_in[3];
  const float* wo = (const float*)d_in[4];
  const float* W1 = (const float*)d_in[5];
  const float* b1 = (const float*)d_in[6];
  const float* gw = (const float*)d_in[7];
  const float* gb = (const float*)d_in[8];

  bf16* ws = (bf16*)d_ws;
  const size_t NEl = (size_t)BB * LL * DD;   // 33,554,432 elems per tensor (64 MiB bf16)
  const size_t WEl = (size_t)DD * DD;        // 4,194,304 elems per weight (8 MiB bf16)
  bf16* Qb = ws;                 // also the scan output O (aliased)
  bf16* Kb = ws + NEl;
  bf16* Vb = (bf16*)d_out;       // V bf16 in d_out's first half (d_out = 128 MiB fp32)

  const size_t need = (2 * NEl + 3 * WEl) * sizeof(bf16);  // 152 MiB primary layout
  if (ws_size >= need) {
    // primary: bf16 A (Xb in d_out 2nd half), 3 BTs in ws tail
    bf16* BTq = ws + 2 * NEl;
    bf16* BTk = BTq + WEl;
    bf16* BTv = BTk + WEl;
    bf16* Xb  = (bf16*)d_out + NEl;
    cast_bf16<<<dim3(16384), 256, 0, stream>>>(X, Xb);
    transpose1<<<dim3(32, 32), 256, 0, stream>>>(wq, BTq);
    transpose1<<<dim3(32, 32), 256, 0, stream>>>(wk, BTk);
    transpose1<<<dim3(32, 32), 256, 0, stream>>>(wv, BTv);
    gemm_qkv<0><<<dim3(16, 128), 512, 0, stream>>>(Xb, BTq, BTk, BTv, Qb, Kb, Vb);
    ttt_scan<<<dim3(256), 256, 0, stream>>>(Qb, Kb, Vb, W1, b1, gw, gb, Qb);
    transpose1<<<dim3(32, 32), 256, 0, stream>>>(wo, BTq);   // BTs consumed; reuse slot
    gemm_bt<1, 0, 0><<<dim3(16, 128), 256, 0, stream>>>(Qb, BTq, d_out);
  } else {
    // fallback (known-safe 136 MiB ws): fp32 A direct, 3 BTs in d_out 2nd half
    bf16* BTq = (bf16*)d_out + NEl;
    bf16* BTk = BTq + WEl;
    bf16* BTv = BTk + WEl;
    bf16* WT  = ws + 2 * NEl;    // 8 MiB slot (known-safe)
    transpose1<<<dim3(32, 32), 256, 0, stream>>>(wq, BTq);
    transpose1<<<dim3(32, 32), 256, 0, stream>>>(wk, BTk);
    transpose1<<<dim3(32, 32), 256, 0, stream>>>(wv, BTv);
    gemm_qkv<1><<<dim3(16, 128), 512, 0, stream>>>(X, BTq, BTk, BTv, Qb, Kb, Vb);
    ttt_scan<<<dim3(256), 256, 0, stream>>>(Qb, Kb, Vb, W1, b1, gw, gb, Qb);
    transpose1<<<dim3(32, 32), 256, 0, stream>>>(wo, WT);
    gemm_bt<1, 0, 0><<<dim3(16, 128), 256, 0, stream>>>(Qb, WT, d_out);
  }
}

// Round 8
// 1074.460 us; speedup vs baseline: 1.2366x; 1.2366x over previous
//
#include <hip/hip_runtime.h>

typedef __bf16 bf16;
typedef __bf16 bf16x4 __attribute__((ext_vector_type(4)));
typedef __bf16 bf16x8 __attribute__((ext_vector_type(8)));
typedef float floatx4 __attribute__((ext_vector_type(4)));

#define BB 8
#define LL 2048
#define DD 2048
#define NHH 32
#define HDD 64

#define MFMA16(a, b, c) __builtin_amdgcn_mfma_f32_16x16x32_bf16(a, b, c, 0, 0, 0)

// async global->LDS DMA, 16B per lane; dest = wave-uniform base + lane*16
__device__ __forceinline__ void gl_lds16(const void* g, void* l) {
  __builtin_amdgcn_global_load_lds((const __attribute__((address_space(1))) void*)g,
                                   (__attribute__((address_space(3))) void*)l, 16, 0, 0);
}

// ---------------- fp32 -> bf16 bulk cast ----------------
__global__ __launch_bounds__(256) void cast_bf16(const float* __restrict__ src,
                                                 bf16* __restrict__ dst)
{
  size_t i = ((size_t)blockIdx.x * 256 + threadIdx.x) * 8;
  floatx4 a = *(const floatx4*)(src + i);
  floatx4 b = *(const floatx4*)(src + i + 4);
  bf16x8 v;
  v[0] = (bf16)a[0]; v[1] = (bf16)a[1]; v[2] = (bf16)a[2]; v[3] = (bf16)a[3];
  v[4] = (bf16)b[0]; v[5] = (bf16)b[1]; v[6] = (bf16)b[2]; v[7] = (bf16)b[3];
  *(bf16x8*)(dst + i) = v;
}

// ---------------- weight transpose + cast: WT[n][k] = (bf16)W[k][n] ----------------
__global__ __launch_bounds__(256) void transpose1(const float* __restrict__ src,
                                                  bf16* __restrict__ dst)
{
  __shared__ float tile[64][65];
  const int t = threadIdx.x;
  const int col = t & 63, rw = t >> 6;
  const int bx = blockIdx.x * 64, by = blockIdx.y * 64;
  for (int i = rw; i < 64; i += 4)
    tile[i][col] = src[(size_t)(by + i) * DD + bx + col];
  __syncthreads();
  for (int i = rw; i < 64; i += 4)
    dst[(size_t)(bx + i) * DD + by + col] = (bf16)tile[col][i];
}

// ---------------- pipelined GEMM: C[16384][2048] = A x B, BT[n][k] bf16 --------------
// Tile 256x256, 8 waves (2M x 4N, 128x64 out/wave), K-step 32.
// LDS: 4-slot ring of {A,B} planes (16 KB each, [256 rows][32 cols]) = 128 KiB.
// Per K-step st: vmcnt(8)+s_barrier -> issue stage(st+3) (4 DMA/thread) ->
// 12 ds_read_b128 -> 32 MFMA (setprio) -> lgkmcnt(0). Counted vmcnt: stages get
// ~3 K-steps to land, never drained to 0 (T3+T4). Hazards:
//   RAW: vmcnt(8) leaves only stages st+1,st+2 in flight -> st landed; barrier joins.
//   WAR: stage(st+3) writes slot (st-1)&3; its readers passed lgkmcnt(0) before the
//        barrier every wave just crossed.
// XOR chunk-swizzle (chunk ^= row&3) on global source and ds_read side (0-conflict,
// measured). RP==1: RoPE fused in epilogue. AIDX/EPI as before.
template<int AIDX, int EPI, int RP>
__global__ __launch_bounds__(512) void gemm256(const bf16* __restrict__ Ab,
    const bf16* __restrict__ BT, void* __restrict__ Cv)
{
  constexpr int NT = 64;                        // 2048 / 32 K-steps
  __shared__ alignas(16) bf16 P[4][2][8192];    // [slot][A|B][256x32]  128 KiB
  const int t = threadIdx.x;
  // XCD swizzle: 512 wgs, 512%8==0 -> bijective remap.
  const int id = blockIdx.y * 8 + blockIdx.x;
  const int swz = (id & 7) * 64 + (id >> 3);
  const int bm = swz >> 3, bn = swz & 7;
  const int wv = t >> 6, lane = t & 63;
  const int q = lane >> 4, i16 = lane & 15;
  const int wm = wv >> 2, wn = wv & 3;          // 2(M) x 4(N) wave grid

  floatx4 acc[8][4] = {};                       // 128 VGPR accumulator

  // staging geometry: thread covers rows srow[j] (j=0,1), swizzled chunk cswz
  const int cswz = ((lane & 3) ^ ((lane >> 2) & 3)) * 8;
  int srow[2];
  srow[0] = wv * 16 + (lane >> 2);
  srow[1] = 128 + wv * 16 + (lane >> 2);
  size_t aSrc[2], bSrc[2];
#pragma unroll
  for (int j = 0; j < 2; ++j) {
    int rA = bm * 256 + srow[j];
    if (AIDX == 0) {
      aSrc[j] = (size_t)rA * DD + cswz;
    } else {
      int b = rA >> 11, l = rA & 2047;
      aSrc[j] = ((size_t)b * NHH * LL + l) * HDD + cswz;  // + (st>>1)*LL*HDD + (st&1)*32
    }
    bSrc[j] = (size_t)(bn * 256 + srow[j]) * DD + cswz;
  }

  auto STAGE = [&](int st) {
    const int slot = st & 3;
#pragma unroll
    for (int j = 0; j < 2; ++j) {
      const bf16* ga;
      if (AIDX == 0) ga = Ab + aSrc[j] + st * 32;
      else           ga = Ab + aSrc[j] + (size_t)(st >> 1) * (LL * HDD) + (st & 1) * 32;
      gl_lds16(ga, &P[slot][0][(j * 8 + wv) * 512]);
      gl_lds16(BT + bSrc[j] + st * 32, &P[slot][1][(j * 8 + wv) * 512]);
    }
  };

  STAGE(0); STAGE(1); STAGE(2);                 // 12 loads in flight

  for (int st = 0; st < NT; ++st) {
    asm volatile("s_waitcnt vmcnt(8)\n\ts_barrier" ::: "memory");
    STAGE((st + 3) & (NT - 1));                 // tail wraps: valid-but-unused restage
    const bf16* Ap = &P[st & 3][0][0];
    const bf16* Bp = &P[st & 3][1][0];
    bf16x8 af[8], bfr[4];
#pragma unroll
    for (int nt = 0; nt < 4; ++nt) {
      int r = wn * 64 + nt * 16 + i16;
      bfr[nt] = *(const bf16x8*)&Bp[r * 32 + ((q ^ (r & 3)) << 3)];
    }
#pragma unroll
    for (int mt = 0; mt < 8; ++mt) {
      int r = wm * 128 + mt * 16 + i16;
      af[mt] = *(const bf16x8*)&Ap[r * 32 + ((q ^ (r & 3)) << 3)];
    }
    __builtin_amdgcn_s_setprio(1);
#pragma unroll
    for (int mt = 0; mt < 8; ++mt)
#pragma unroll
      for (int nt = 0; nt < 4; ++nt)
        acc[mt][nt] = MFMA16(af[mt], bfr[nt], acc[mt][nt]);
    __builtin_amdgcn_s_setprio(0);
    asm volatile("s_waitcnt lgkmcnt(0)" ::: "memory");  // all reads of this slot done
  }

  // ---- epilogue ----
  float invf[4];
  if (RP) {
#pragma unroll
    for (int nt = 0; nt < 4; ++nt) {
      int col = bn * 256 + wn * 64 + nt * 16 + i16;
      invf[nt] = __expf(-(float)((col >> 1) & 31) * 0.28782313662425573f);
    }
  }
#pragma unroll
  for (int mt = 0; mt < 8; ++mt)
#pragma unroll
    for (int nt = 0; nt < 4; ++nt)
#pragma unroll
      for (int rg = 0; rg < 4; ++rg) {
        int row = bm * 256 + wm * 128 + mt * 16 + q * 4 + rg;
        int col = bn * 256 + wn * 64 + nt * 16 + i16;
        float v = acc[mt][nt][rg];
        if (RP) {
          float o = __shfl_xor(v, 1, 64);       // partner feature (adjacent lane)
          float sn, cs;
          __sincosf((float)(row & 2047) * invf[nt], &sn, &cs);
          v = (i16 & 1) ? (v * cs + o * sn) : (v * cs - o * sn);
        }
        if (EPI == 0) {
          ((float*)Cv)[(size_t)row * DD + col] = v;
        } else {
          int b = row >> 11, l = row & 2047;
          int h = col >> 6, f = col & 63;
          ((bf16*)Cv)[((size_t)(b * NHH + h) * LL + l) * HDD + f] = (bf16)v;
        }
      }
}

// ---------------- TTT scan v3 (round-6 best, unchanged): 4 waves, 3 barriers/chunk ----
__global__ __launch_bounds__(256) void ttt_scan(
    const bf16* Q, const bf16* __restrict__ Kx,
    const bf16* __restrict__ V, const float* __restrict__ W1g,
    const float* __restrict__ b1g, const float* __restrict__ gw,
    const float* __restrict__ gb, bf16* O)
{
  const int bh = blockIdx.x, h = bh & 31;
  const int t = threadIdx.x;
  const int wave = t >> 6, lane = t & 63;
  const int q = lane >> 4, i16 = lane & 15;
  const int kr = t >> 4, sr = t & 15, f0 = sr * 4;

  __shared__ alignas(16) bf16 W1Th[64 * 72];
  __shared__ alignas(16) bf16 W1Tl[64 * 72];
  __shared__ alignas(16) bf16 xkTs[64 * 24];
  __shared__ alignas(16) bf16 gTh[64 * 24];
  __shared__ alignas(16) bf16 gTl[64 * 24];
  __shared__ alignas(16) bf16 Pm[16 * 24];
  __shared__ alignas(16) float Z1s[2][16 * 68];

  floatx4 accW[4];
  const float* Wg = W1g + (size_t)h * 4096;
  for (int mt = 0; mt < 4; ++mt)
    for (int r = 0; r < 4; ++r)
      accW[mt][r] = Wg[(16 * mt + 4 * q + r) * 64 + 16 * wave + i16];
  float b1r = b1g[h * 64 + 16 * wave + i16];

  for (int mt = 0; mt < 4; ++mt) {
    bf16x4 h4, l4;
    for (int r = 0; r < 4; ++r) {
      float w = accW[mt][r];
      bf16 hi = (bf16)w;
      h4[r] = hi; l4[r] = (bf16)(w - (float)hi);
    }
    int base = (16 * wave + i16) * 72 + 16 * mt + 4 * q;
    *(bf16x4*)&W1Th[base] = h4;
    *(bf16x4*)&W1Tl[base] = l4;
  }

  float gq[4], bq[4];
  for (int j = 0; j < 4; ++j) {
    gq[j] = gw[h * 64 + f0 + j];
    bq[j] = gb[h * 64 + f0 + j];
  }
  float etar[4];
  for (int r = 0; r < 4; ++r) etar[r] = 1.0f / (float)(4 * q + r + 1);

  const size_t qbase = (size_t)bh * (LL * HDD);
  const int foff = i16 * 64 + q * 8;
  const int poff = kr * 64 + f0;

  bf16x8 ak0 = *(const bf16x8*)(Kx + qbase + foff);
  bf16x8 ak1 = *(const bf16x8*)(Kx + qbase + foff + 32);
  bf16x8 aq0 = *(const bf16x8*)(Q  + qbase + foff);
  bf16x8 aq1 = *(const bf16x8*)(Q  + qbase + foff + 32);
  bf16x4 rq = *(const bf16x4*)(Q  + qbase + poff);
  bf16x4 rk = *(const bf16x4*)(Kx + qbase + poff);
  bf16x4 rv = *(const bf16x4*)(V  + qbase + poff);

  __syncthreads();

  for (int c = 0; c < 128; ++c) {
    const int pb = c & 1;
    for (int j = 0; j < 4; ++j)
      xkTs[(f0 + j) * 24 + kr] = (bf16)((float)rk[j] * -0.0625f);

    bf16x8 whi[2], wlo[2];
    {
      int wb = (16 * wave + i16) * 72 + q * 8;
      whi[0] = *(const bf16x8*)&W1Th[wb];
      whi[1] = *(const bf16x8*)&W1Th[wb + 32];
      wlo[0] = *(const bf16x8*)&W1Tl[wb];
      wlo[1] = *(const bf16x8*)&W1Tl[wb + 32];
    }
    {
      floatx4 z = {b1r, b1r, b1r, b1r};
      z = MFMA16(ak0, whi[0], z);
      z = MFMA16(ak1, whi[1], z);
      z = MFMA16(ak0, wlo[0], z);
      z = MFMA16(ak1, wlo[1], z);
      for (int r = 0; r < 4; ++r)
        Z1s[pb][(4 * q + r) * 68 + 16 * wave + i16] = z[r];
    }
    if (wave == 0) {
      floatx4 at = {};
      at = MFMA16(aq0, ak0, at);
      at = MFMA16(aq1, ak1, at);
      for (int r = 0; r < 4; ++r) {
        int krow = 4 * q + r;
        float pv = (i16 <= krow) ? -(at[r] + 1.0f) * etar[r] : 0.0f;
        Pm[krow * 24 + i16] = (bf16)pv;
      }
    }
    __syncthreads();   // barrier B

    {
      floatx4 z4 = *(const floatx4*)&Z1s[pb][kr * 68 + f0];
      float tg[4], sum = 0.f, ssq = 0.f;
      for (int j = 0; j < 4; ++j) {
        tg[j] = (float)rv[j] - (float)rk[j];
        sum += z4[j]; ssq += z4[j] * z4[j];
      }
      for (int m = 1; m < 16; m <<= 1) { sum += __shfl_xor(sum, m, 64); ssq += __shfl_xor(ssq, m, 64); }
      float mu = sum * (1.f / 64.f);
      float var = ssq * (1.f / 64.f) - mu * mu;
      float rstd = rsqrtf(var + 1e-6f);
      float xh[4], gx[4], s1 = 0.f, s2 = 0.f;
      for (int j = 0; j < 4; ++j) {
        xh[j] = (z4[j] - mu) * rstd;
        float go = gq[j] * xh[j] + bq[j] - tg[j];
        gx[j] = go * gq[j];
        s1 += gx[j]; s2 += gx[j] * xh[j];
      }
      for (int m = 1; m < 16; m <<= 1) { s1 += __shfl_xor(s1, m, 64); s2 += __shfl_xor(s2, m, 64); }
      for (int j = 0; j < 4; ++j) {
        float gr = (64.f * gx[j] - s1 - xh[j] * s2) * (rstd * (1.f / 64.f));
        bf16 hi = (bf16)gr;
        gTh[(f0 + j) * 24 + kr] = hi;
        gTl[(f0 + j) * 24 + kr] = (bf16)(gr - (float)hi);
      }
    }
    __syncthreads();   // barrier C

    const size_t nb = qbase + (size_t)(c + 1) * 1024;
    bf16x8 nak0 = *(const bf16x8*)(Kx + nb + foff);
    bf16x8 nak1 = *(const bf16x8*)(Kx + nb + foff + 32);
    bf16x8 naq0 = *(const bf16x8*)(Q  + nb + foff);
    bf16x8 naq1 = *(const bf16x8*)(Q  + nb + foff + 32);
    bf16x4 nrq = *(const bf16x4*)(Q  + nb + poff);
    bf16x4 nrk = *(const bf16x4*)(Kx + nb + poff);
    bf16x4 nrv = *(const bf16x4*)(V  + nb + poff);

    {
      bf16x8 pf  = *(const bf16x8*)&Pm[i16 * 24 + (q & 1) * 8];
      const bf16* gT = (q < 2) ? gTh : gTl;
      bf16x8 bgp = *(const bf16x8*)&gT[(16 * wave + i16) * 24 + (q & 1) * 8];
      floatx4 zb = {b1r, b1r, b1r, b1r};
      zb = MFMA16(aq0, whi[0], zb);
      zb = MFMA16(aq1, whi[1], zb);
      zb = MFMA16(aq0, wlo[0], zb);
      zb = MFMA16(aq1, wlo[1], zb);
      zb = MFMA16(pf, bgp, zb);
      for (int r = 0; r < 4; ++r)
        Z1s[pb][(4 * q + r) * 68 + 16 * wave + i16] = zb[r];

      for (int mt = 0; mt < 4; ++mt) {
        bf16x8 axk = *(const bf16x8*)&xkTs[(16 * mt + i16) * 24 + (q & 1) * 8];
        accW[mt] = MFMA16(axk, bgp, accW[mt]);
      }
      for (int mt = 0; mt < 4; ++mt) {
        bf16x4 h4, l4;
        for (int r = 0; r < 4; ++r) {
          float w = accW[mt][r];
          bf16 hi = (bf16)w;
          h4[r] = hi; l4[r] = (bf16)(w - (float)hi);
        }
        int base = (16 * wave + i16) * 72 + 16 * mt + 4 * q;
        *(bf16x4*)&W1Th[base] = h4;
        *(bf16x4*)&W1Tl[base] = l4;
      }
      {
        const bf16* rh = &gTh[(16 * wave + i16) * 24];
        const bf16* rl = &gTl[(16 * wave + i16) * 24];
        bf16x8 a0 = *(const bf16x8*)rh, a1 = *(const bf16x8*)(rh + 8);
        bf16x8 a2 = *(const bf16x8*)rl, a3 = *(const bf16x8*)(rl + 8);
        float s = 0.f;
        for (int j = 0; j < 8; ++j)
          s += (float)a0[j] + (float)a1[j] + (float)a2[j] + (float)a3[j];
        b1r -= 0.0625f * s;
      }
    }
    __syncthreads();   // barrier D

    {
      floatx4 z4 = *(const floatx4*)&Z1s[pb][kr * 68 + f0];
      float sum = 0.f, ssq = 0.f;
      for (int j = 0; j < 4; ++j) { sum += z4[j]; ssq += z4[j] * z4[j]; }
      for (int m = 1; m < 16; m <<= 1) { sum += __shfl_xor(sum, m, 64); ssq += __shfl_xor(ssq, m, 64); }
      float mu = sum * (1.f / 64.f);
      float var = ssq * (1.f / 64.f) - mu * mu;
      float rstd = rsqrtf(var + 1e-6f);
      bf16x4 o4;
      for (int j = 0; j < 4; ++j)
        o4[j] = (bf16)((float)rq[j] + gq[j] * ((z4[j] - mu) * rstd) + bq[j]);
      *(bf16x4*)(O + qbase + (size_t)c * 1024 + poff) = o4;
    }
    ak0 = nak0; ak1 = nak1; aq0 = naq0; aq1 = naq1;
    rq = nrq; rk = nrk; rv = nrv;
  }
}

extern "C" void kernel_launch(void* const* d_in, const int* in_sizes, int n_in,
                              void* d_out, int out_size, void* d_ws, size_t ws_size,
                              hipStream_t stream)
{
  const float* X  = (const float*)d_in[0];
  const float* wq = (const float*)d_in[1];
  const float* wk = (const float*)d_in[2];
  const float* wv = (const float*)d_in[3];
  const float* wo = (const float*)d_in[4];
  const float* W1 = (const float*)d_in[5];
  const float* b1 = (const float*)d_in[6];
  const float* gw = (const float*)d_in[7];
  const float* gb = (const float*)d_in[8];

  bf16* ws = (bf16*)d_ws;
  const size_t NEl = (size_t)BB * LL * DD;   // 33,554,432 elems per tensor (64 MiB bf16)
  bf16* Qb = ws;                 // also the scan output O (aliased)
  bf16* Kb = ws + NEl;
  bf16* WT = ws + 2 * NEl;       // single transposed-weight slot, reused (8 MiB)
  bf16* Vb = (bf16*)d_out;       // V bf16 in d_out first half
  bf16* Xb = (bf16*)d_out + NEl; // X bf16 in d_out second half; both consumed
                                 // before the final GEMM overwrites d_out.

  cast_bf16<<<dim3(16384), 256, 0, stream>>>(X, Xb);
  transpose1<<<dim3(32, 32), 256, 0, stream>>>(wq, WT);
  gemm256<0, 1, 1><<<dim3(8, 64), 512, 0, stream>>>(Xb, WT, Qb);   // Q + RoPE
  transpose1<<<dim3(32, 32), 256, 0, stream>>>(wk, WT);
  gemm256<0, 1, 1><<<dim3(8, 64), 512, 0, stream>>>(Xb, WT, Kb);   // K + RoPE
  transpose1<<<dim3(32, 32), 256, 0, stream>>>(wv, WT);
  gemm256<0, 1, 0><<<dim3(8, 64), 512, 0, stream>>>(Xb, WT, Vb);   // V
  ttt_scan<<<dim3(256), 256, 0, stream>>>(Qb, Kb, Vb, W1, b1, gw, gb, Qb);
  transpose1<<<dim3(32, 32), 256, 0, stream>>>(wo, WT);
  gemm256<1, 0, 0><<<dim3(8, 64), 512, 0, stream>>>(Qb, WT, d_out); // Wo
}

// Round 9
// 1020.817 us; speedup vs baseline: 1.3016x; 1.0525x over previous
//
#include <hip/hip_runtime.h>

typedef __bf16 bf16;
typedef __bf16 bf16x4 __attribute__((ext_vector_type(4)));
typedef __bf16 bf16x8 __attribute__((ext_vector_type(8)));
typedef float floatx4 __attribute__((ext_vector_type(4)));

#define BB 8
#define LL 2048
#define DD 2048
#define NHH 32
#define HDD 64

#define MFMA16(a, b, c) __builtin_amdgcn_mfma_f32_16x16x32_bf16(a, b, c, 0, 0, 0)

// async global->LDS DMA, 16B per lane; dest = wave-uniform base + lane*16
__device__ __forceinline__ void gl_lds16(const void* g, void* l) {
  __builtin_amdgcn_global_load_lds((const __attribute__((address_space(1))) void*)g,
                                   (__attribute__((address_space(3))) void*)l, 16, 0, 0);
}

// ---------------- fp32 -> bf16 bulk cast ----------------
__global__ __launch_bounds__(256) void cast_bf16(const float* __restrict__ src,
                                                 bf16* __restrict__ dst)
{
  size_t i = ((size_t)blockIdx.x * 256 + threadIdx.x) * 8;
  floatx4 a = *(const floatx4*)(src + i);
  floatx4 b = *(const floatx4*)(src + i + 4);
  bf16x8 v;
  v[0] = (bf16)a[0]; v[1] = (bf16)a[1]; v[2] = (bf16)a[2]; v[3] = (bf16)a[3];
  v[4] = (bf16)b[0]; v[5] = (bf16)b[1]; v[6] = (bf16)b[2]; v[7] = (bf16)b[3];
  *(bf16x8*)(dst + i) = v;
}

// ---------------- weight transpose + cast: WT[n][k] = (bf16)W[k][n] ----------------
__global__ __launch_bounds__(256) void transpose1(const float* __restrict__ src,
                                                  bf16* __restrict__ dst)
{
  __shared__ float tile[64][65];
  const int t = threadIdx.x;
  const int col = t & 63, rw = t >> 6;
  const int bx = blockIdx.x * 64, by = blockIdx.y * 64;
  for (int i = rw; i < 64; i += 4)
    tile[i][col] = src[(size_t)(by + i) * DD + bx + col];
  __syncthreads();
  for (int i = rw; i < 64; i += 4)
    dst[(size_t)(bx + i) * DD + by + col] = (bf16)tile[col][i];
}

// ---------------- pipelined GEMM: C[16384][2048] = A x B, BT[n][k] bf16 --------------
// Tile 256x256, 8 waves (2M x 4N, 128x64 out/wave), K-step 32.
// LDS: 4-slot ring of {A,B} planes (16 KB each) = 128 KiB. Per K-step st:
// vmcnt(8)+s_barrier -> issue stage(st+3) -> staggered ds_reads + 32 MFMA ->
// lgkmcnt(0). Counted vmcnt: stages get ~3 K-steps to land, never drained to 0.
// Hazards: RAW: vmcnt(8) leaves only st+1,st+2 in flight -> st landed; barrier joins.
//          WAR: stage(st+3) writes slot (st-1)&3; readers passed lgkmcnt(0) pre-barrier.
// setprio removed (m190: negative in lockstep-barrier GEMM). Unroll 4: slot indices
// become compile-time. af reads staggered between MFMA clusters.
template<int AIDX, int EPI, int RP>
__global__ __launch_bounds__(512) void gemm256(const bf16* __restrict__ Ab,
    const bf16* __restrict__ BT, void* __restrict__ Cv)
{
  constexpr int NT = 64;                        // 2048 / 32 K-steps
  __shared__ alignas(16) bf16 P[4][2][8192];    // [slot][A|B][256x32]  128 KiB
  const int t = threadIdx.x;
  // XCD swizzle: 512 wgs, 512%8==0 -> bijective remap.
  const int id = blockIdx.y * 8 + blockIdx.x;
  const int swz = (id & 7) * 64 + (id >> 3);
  const int bm = swz >> 3, bn = swz & 7;
  const int wv = t >> 6, lane = t & 63;
  const int q = lane >> 4, i16 = lane & 15;
  const int wm = wv >> 2, wn = wv & 3;          // 2(M) x 4(N) wave grid

  floatx4 acc[8][4] = {};                       // 128 VGPR accumulator

  const int cswz = ((lane & 3) ^ ((lane >> 2) & 3)) * 8;
  int srow[2];
  srow[0] = wv * 16 + (lane >> 2);
  srow[1] = 128 + wv * 16 + (lane >> 2);
  size_t aSrc[2], bSrc[2];
#pragma unroll
  for (int j = 0; j < 2; ++j) {
    int rA = bm * 256 + srow[j];
    if (AIDX == 0) {
      aSrc[j] = (size_t)rA * DD + cswz;
    } else {
      int b = rA >> 11, l = rA & 2047;
      aSrc[j] = ((size_t)b * NHH * LL + l) * HDD + cswz;  // + (st>>1)*LL*HDD + (st&1)*32
    }
    bSrc[j] = (size_t)(bn * 256 + srow[j]) * DD + cswz;
  }

  auto STAGE = [&](int st) {
    const int slot = st & 3;
#pragma unroll
    for (int j = 0; j < 2; ++j) {
      const bf16* ga;
      if (AIDX == 0) ga = Ab + aSrc[j] + st * 32;
      else           ga = Ab + aSrc[j] + (size_t)(st >> 1) * (LL * HDD) + (st & 1) * 32;
      gl_lds16(ga, &P[slot][0][(j * 8 + wv) * 512]);
      gl_lds16(BT + bSrc[j] + st * 32, &P[slot][1][(j * 8 + wv) * 512]);
    }
  };

  STAGE(0); STAGE(1); STAGE(2);                 // 12 loads in flight

#pragma unroll 4
  for (int st = 0; st < NT; ++st) {
    asm volatile("s_waitcnt vmcnt(8)\n\ts_barrier" ::: "memory");
    STAGE((st + 3) & (NT - 1));                 // tail wraps: valid-but-unused restage
    const bf16* Ap = &P[st & 3][0][0];
    const bf16* Bp = &P[st & 3][1][0];
    bf16x8 af[8], bfr[4];
#pragma unroll
    for (int nt = 0; nt < 4; ++nt) {
      int r = wn * 64 + nt * 16 + i16;
      bfr[nt] = *(const bf16x8*)&Bp[r * 32 + ((q ^ (r & 3)) << 3)];
    }
    {
      int r0 = wm * 128 + i16;
      af[0] = *(const bf16x8*)&Ap[r0 * 32 + ((q ^ (r0 & 3)) << 3)];
      int r1 = wm * 128 + 16 + i16;
      af[1] = *(const bf16x8*)&Ap[r1 * 32 + ((q ^ (r1 & 3)) << 3)];
    }
#pragma unroll
    for (int mt = 0; mt < 8; ++mt) {
      if (mt < 6) {
        int r = wm * 128 + (mt + 2) * 16 + i16;
        af[mt + 2] = *(const bf16x8*)&Ap[r * 32 + ((q ^ (r & 3)) << 3)];
      }
#pragma unroll
      for (int nt = 0; nt < 4; ++nt)
        acc[mt][nt] = MFMA16(af[mt], bfr[nt], acc[mt][nt]);
    }
    asm volatile("s_waitcnt lgkmcnt(0)" ::: "memory");  // all reads of this slot done
  }

  // ---- epilogue ----
  float invf[4];
  if (RP) {
#pragma unroll
    for (int nt = 0; nt < 4; ++nt) {
      int col = bn * 256 + wn * 64 + nt * 16 + i16;
      invf[nt] = __expf(-(float)((col >> 1) & 31) * 0.28782313662425573f);
    }
  }
#pragma unroll
  for (int mt = 0; mt < 8; ++mt)
#pragma unroll
    for (int nt = 0; nt < 4; ++nt)
#pragma unroll
      for (int rg = 0; rg < 4; ++rg) {
        int row = bm * 256 + wm * 128 + mt * 16 + q * 4 + rg;
        int col = bn * 256 + wn * 64 + nt * 16 + i16;
        float v = acc[mt][nt][rg];
        if (RP) {
          float o = __shfl_xor(v, 1, 64);       // partner feature (adjacent lane)
          float sn, cs;
          __sincosf((float)(row & 2047) * invf[nt], &sn, &cs);
          v = (i16 & 1) ? (v * cs + o * sn) : (v * cs - o * sn);
        }
        if (EPI == 0) {
          ((float*)Cv)[(size_t)row * DD + col] = v;
        } else {
          int b = row >> 11, l = row & 2047;
          int h = col >> 6, f = col & 63;
          ((bf16*)Cv)[((size_t)(b * NHH + h) * LL + l) * HDD + f] = (bf16)v;
        }
      }
}

// ---------------- TTT scan v4: 4 waves, 3 barriers/chunk, chunk-swizzled scatters -----
// The transposed scatter buffers (xkTs/gTh/gTl, [row=f-or-g][k], pitch 24) had 16-way
// write conflicts (16 sr-lanes collapse mod 2 at 48B pitch). Fix: XOR the k-CHUNK bit
// with row bit 3: storage[row][k ^ ((row>>3)&1)<<3]. Readers flip the same bit from
// their row index -> retrieved logical k unchanged (MFMA operand k-mappings still
// match; b1 row-sums order-invariant). Writes 16->8-way; b128 reads stay ~2-way.
__global__ __launch_bounds__(256) void ttt_scan(
    const bf16* Q, const bf16* __restrict__ Kx,
    const bf16* __restrict__ V, const float* __restrict__ W1g,
    const float* __restrict__ b1g, const float* __restrict__ gw,
    const float* __restrict__ gb, bf16* O)
{
  const int bh = blockIdx.x, h = bh & 31;
  const int t = threadIdx.x;
  const int wave = t >> 6, lane = t & 63;
  const int q = lane >> 4, i16 = lane & 15;
  const int kr = t >> 4, sr = t & 15, f0 = sr * 4;

  __shared__ alignas(16) bf16 W1Th[64 * 72];
  __shared__ alignas(16) bf16 W1Tl[64 * 72];
  __shared__ alignas(16) bf16 xkTs[64 * 24];
  __shared__ alignas(16) bf16 gTh[64 * 24];
  __shared__ alignas(16) bf16 gTl[64 * 24];
  __shared__ alignas(16) bf16 Pm[16 * 24];
  __shared__ alignas(16) float Z1s[2][16 * 68];

  floatx4 accW[4];
  const float* Wg = W1g + (size_t)h * 4096;
  for (int mt = 0; mt < 4; ++mt)
    for (int r = 0; r < 4; ++r)
      accW[mt][r] = Wg[(16 * mt + 4 * q + r) * 64 + 16 * wave + i16];
  float b1r = b1g[h * 64 + 16 * wave + i16];

  for (int mt = 0; mt < 4; ++mt) {
    bf16x4 h4, l4;
    for (int r = 0; r < 4; ++r) {
      float w = accW[mt][r];
      bf16 hi = (bf16)w;
      h4[r] = hi; l4[r] = (bf16)(w - (float)hi);
    }
    int base = (16 * wave + i16) * 72 + 16 * mt + 4 * q;
    *(bf16x4*)&W1Th[base] = h4;
    *(bf16x4*)&W1Tl[base] = l4;
  }

  float gq[4], bq[4];
  for (int j = 0; j < 4; ++j) {
    gq[j] = gw[h * 64 + f0 + j];
    bq[j] = gb[h * 64 + f0 + j];
  }
  float etar[4];
  for (int r = 0; r < 4; ++r) etar[r] = 1.0f / (float)(4 * q + r + 1);

  // scatter-write k index (swizzled) and reader chunk offsets (swizzled)
  const int krSwz = kr ^ (((sr >> 1) & 1) << 3);         // bit3 of f = (sr>>1)&1
  const int rdChunk = (((q & 1) ^ ((i16 >> 3) & 1)) << 3); // readers' row = 16*w + i16

  const size_t qbase = (size_t)bh * (LL * HDD);
  const int foff = i16 * 64 + q * 8;
  const int poff = kr * 64 + f0;

  bf16x8 ak0 = *(const bf16x8*)(Kx + qbase + foff);
  bf16x8 ak1 = *(const bf16x8*)(Kx + qbase + foff + 32);
  bf16x8 aq0 = *(const bf16x8*)(Q  + qbase + foff);
  bf16x8 aq1 = *(const bf16x8*)(Q  + qbase + foff + 32);
  bf16x4 rq = *(const bf16x4*)(Q  + qbase + poff);
  bf16x4 rk = *(const bf16x4*)(Kx + qbase + poff);
  bf16x4 rv = *(const bf16x4*)(V  + qbase + poff);

  __syncthreads();   // W1T init visible

  for (int c = 0; c < 128; ++c) {
    const int pb = c & 1;
    // ---- xkT scatter (swizzled k) ----
    for (int j = 0; j < 4; ++j)
      xkTs[(f0 + j) * 24 + krSwz] = (bf16)((float)rk[j] * -0.0625f);

    // ---- stage 1: Z1 = xk @ W1 + b1 (all waves); attn -> P (wave 0) ----
    bf16x8 whi[2], wlo[2];
    {
      int wb = (16 * wave + i16) * 72 + q * 8;
      whi[0] = *(const bf16x8*)&W1Th[wb];
      whi[1] = *(const bf16x8*)&W1Th[wb + 32];
      wlo[0] = *(const bf16x8*)&W1Tl[wb];
      wlo[1] = *(const bf16x8*)&W1Tl[wb + 32];
    }
    {
      floatx4 z = {b1r, b1r, b1r, b1r};
      z = MFMA16(ak0, whi[0], z);
      z = MFMA16(ak1, whi[1], z);
      z = MFMA16(ak0, wlo[0], z);
      z = MFMA16(ak1, wlo[1], z);
      for (int r = 0; r < 4; ++r)
        Z1s[pb][(4 * q + r) * 68 + 16 * wave + i16] = z[r];
    }
    if (wave == 0) {
      floatx4 at = {};
      at = MFMA16(aq0, ak0, at);
      at = MFMA16(aq1, ak1, at);
      for (int r = 0; r < 4; ++r) {
        int krow = 4 * q + r;
        float pv = (i16 <= krow) ? -(at[r] + 1.0f) * etar[r] : 0.0f;
        Pm[krow * 24 + i16] = (bf16)pv;
      }
    }
    __syncthreads();   // barrier B

    // ---- stage B: LN fused-l2 backward -> grad^T hi/lo (swizzled k) ----
    {
      floatx4 z4 = *(const floatx4*)&Z1s[pb][kr * 68 + f0];
      float tg[4], sum = 0.f, ssq = 0.f;
      for (int j = 0; j < 4; ++j) {
        tg[j] = (float)rv[j] - (float)rk[j];
        sum += z4[j]; ssq += z4[j] * z4[j];
      }
      for (int m = 1; m < 16; m <<= 1) { sum += __shfl_xor(sum, m, 64); ssq += __shfl_xor(ssq, m, 64); }
      float mu = sum * (1.f / 64.f);
      float var = ssq * (1.f / 64.f) - mu * mu;
      float rstd = rsqrtf(var + 1e-6f);
      float xh[4], gx[4], s1 = 0.f, s2 = 0.f;
      for (int j = 0; j < 4; ++j) {
        xh[j] = (z4[j] - mu) * rstd;
        float go = gq[j] * xh[j] + bq[j] - tg[j];
        gx[j] = go * gq[j];
        s1 += gx[j]; s2 += gx[j] * xh[j];
      }
      for (int m = 1; m < 16; m <<= 1) { s1 += __shfl_xor(s1, m, 64); s2 += __shfl_xor(s2, m, 64); }
      for (int j = 0; j < 4; ++j) {
        float gr = (64.f * gx[j] - s1 - xh[j] * s2) * (rstd * (1.f / 64.f));
        bf16 hi = (bf16)gr;
        gTh[(f0 + j) * 24 + krSwz] = hi;
        gTl[(f0 + j) * 24 + krSwz] = (bf16)(gr - (float)hi);
      }
    }
    __syncthreads();   // barrier C

    // ---- prefetch chunk c+1 (c=127 reads spill harmlessly into adjacent buffers) ----
    const size_t nb = qbase + (size_t)(c + 1) * 1024;
    bf16x8 nak0 = *(const bf16x8*)(Kx + nb + foff);
    bf16x8 nak1 = *(const bf16x8*)(Kx + nb + foff + 32);
    bf16x8 naq0 = *(const bf16x8*)(Q  + nb + foff);
    bf16x8 naq1 = *(const bf16x8*)(Q  + nb + foff + 32);
    bf16x4 nrq = *(const bf16x4*)(Q  + nb + poff);
    bf16x4 nrk = *(const bf16x4*)(Kx + nb + poff);
    bf16x4 nrv = *(const bf16x4*)(V  + nb + poff);

    // ---- stage C: Zbar = xq@W1 + P@grad + b1 ; accW update; W1T repack; b1 ----
    {
      bf16x8 pf  = *(const bf16x8*)&Pm[i16 * 24 + (q & 1) * 8];
      const bf16* gT = (q < 2) ? gTh : gTl;    // K=32 packing: hi halves then lo halves
      bf16x8 bgp = *(const bf16x8*)&gT[(16 * wave + i16) * 24 + rdChunk];
      floatx4 zb = {b1r, b1r, b1r, b1r};
      zb = MFMA16(aq0, whi[0], zb);
      zb = MFMA16(aq1, whi[1], zb);
      zb = MFMA16(aq0, wlo[0], zb);
      zb = MFMA16(aq1, wlo[1], zb);
      zb = MFMA16(pf, bgp, zb);                // sums P*(grad_hi+grad_lo)
      for (int r = 0; r < 4; ++r)
        Z1s[pb][(4 * q + r) * 68 + 16 * wave + i16] = zb[r];

      for (int mt = 0; mt < 4; ++mt) {
        // axk row = 16*mt + i16 -> same row-bit3 as i16 -> same rdChunk
        bf16x8 axk = *(const bf16x8*)&xkTs[(16 * mt + i16) * 24 + rdChunk];
        accW[mt] = MFMA16(axk, bgp, accW[mt]);
      }
      for (int mt = 0; mt < 4; ++mt) {
        bf16x4 h4, l4;
        for (int r = 0; r < 4; ++r) {
          float w = accW[mt][r];
          bf16 hi = (bf16)w;
          h4[r] = hi; l4[r] = (bf16)(w - (float)hi);
        }
        int base = (16 * wave + i16) * 72 + 16 * mt + 4 * q;
        *(bf16x4*)&W1Th[base] = h4;
        *(bf16x4*)&W1Tl[base] = l4;
      }
      {
        // full-row sums: chunk contents may be swapped per row; sum is invariant
        const bf16* rh = &gTh[(16 * wave + i16) * 24];
        const bf16* rl = &gTl[(16 * wave + i16) * 24];
        bf16x8 a0 = *(const bf16x8*)rh, a1 = *(const bf16x8*)(rh + 8);
        bf16x8 a2 = *(const bf16x8*)rl, a3 = *(const bf16x8*)(rl + 8);
        float s = 0.f;
        for (int j = 0; j < 8; ++j)
          s += (float)a0[j] + (float)a1[j] + (float)a2[j] + (float)a3[j];
        b1r -= 0.0625f * s;
      }
    }
    __syncthreads();   // barrier D

    // ---- stage E: out = xq + LN_fwd(Zbar) -> O (aliases Q) ----
    {
      floatx4 z4 = *(const floatx4*)&Z1s[pb][kr * 68 + f0];
      float sum = 0.f, ssq = 0.f;
      for (int j = 0; j < 4; ++j) { sum += z4[j]; ssq += z4[j] * z4[j]; }
      for (int m = 1; m < 16; m <<= 1) { sum += __shfl_xor(sum, m, 64); ssq += __shfl_xor(ssq, m, 64); }
      float mu = sum * (1.f / 64.f);
      float var = ssq * (1.f / 64.f) - mu * mu;
      float rstd = rsqrtf(var + 1e-6f);
      bf16x4 o4;
      for (int j = 0; j < 4; ++j)
        o4[j] = (bf16)((float)rq[j] + gq[j] * ((z4[j] - mu) * rstd) + bq[j]);
      *(bf16x4*)(O + qbase + (size_t)c * 1024 + poff) = o4;
    }
    ak0 = nak0; ak1 = nak1; aq0 = naq0; aq1 = naq1;
    rq = nrq; rk = nrk; rv = nrv;
  }
}

extern "C" void kernel_launch(void* const* d_in, const int* in_sizes, int n_in,
                              void* d_out, int out_size, void* d_ws, size_t ws_size,
                              hipStream_t stream)
{
  const float* X  = (const float*)d_in[0];
  const float* wq = (const float*)d_in[1];
  const float* wk = (const float*)d_in[2];
  const float* wv = (const float*)d_in[3];
  const float* wo = (const float*)d_in[4];
  const float* W1 = (const float*)d_in[5];
  const float* b1 = (const float*)d_in[6];
  const float* gw = (const float*)d_in[7];
  const float* gb = (const float*)d_in[8];

  bf16* ws = (bf16*)d_ws;
  const size_t NEl = (size_t)BB * LL * DD;   // 33,554,432 elems per tensor (64 MiB bf16)
  bf16* Qb = ws;                 // also the scan output O (aliased)
  bf16* Kb = ws + NEl;
  bf16* WT = ws + 2 * NEl;       // single transposed-weight slot, reused (8 MiB)
  bf16* Vb = (bf16*)d_out;       // V bf16 in d_out first half
  bf16* Xb = (bf16*)d_out + NEl; // X bf16 in d_out second half; both consumed
                                 // before the final GEMM overwrites d_out.

  cast_bf16<<<dim3(16384), 256, 0, stream>>>(X, Xb);
  transpose1<<<dim3(32, 32), 256, 0, stream>>>(wq, WT);
  gemm256<0, 1, 1><<<dim3(8, 64), 512, 0, stream>>>(Xb, WT, Qb);   // Q + RoPE
  transpose1<<<dim3(32, 32), 256, 0, stream>>>(wk, WT);
  gemm256<0, 1, 1><<<dim3(8, 64), 512, 0, stream>>>(Xb, WT, Kb);   // K + RoPE
  transpose1<<<dim3(32, 32), 256, 0, stream>>>(wv, WT);
  gemm256<0, 1, 0><<<dim3(8, 64), 512, 0, stream>>>(Xb, WT, Vb);   // V
  ttt_scan<<<dim3(256), 256, 0, stream>>>(Qb, Kb, Vb, W1, b1, gw, gb, Qb);
  transpose1<<<dim3(32, 32), 256, 0, stream>>>(wo, WT);
  gemm256<1, 0, 0><<<dim3(8, 64), 512, 0, stream>>>(Qb, WT, d_out); // Wo
}